// Round 3
// baseline (780.682 us; speedup 1.0000x reference)
//
#include <hip/hip_runtime.h>
#include <hip/hip_bf16.h>
#include <stdint.h>

#define B_    256
#define T_    512
#define N_    256
#define START_ 254
#define STOP_  255
#define GCOLS 16
#define NDB   (B_ / GCOLS)   // 16 denominator blocks
#define LOG2E 1.4426950408889634f
#define LN2   0.6931471805599453f

typedef __attribute__((ext_vector_type(8))) short short8;
typedef __attribute__((ext_vector_type(4))) short short4_t;
typedef __attribute__((ext_vector_type(4))) float floatx4;

__device__ __forceinline__ short f2bf(float f) {        // RNE (one-time E build)
    uint32_t u = __builtin_bit_cast(uint32_t, f);
    u = (u + 0x7FFFu + ((u >> 16) & 1u)) >> 16;
    return (short)(uint16_t)u;
}
__device__ __forceinline__ short f2bf_fast(float f) {   // round-half-up (per step)
    uint32_t u = __builtin_bit_cast(uint32_t, f);
    return (short)((u + 0x8000u) >> 16);
}

// lgkm-only barrier: LDS data drained, global prefetch stays in flight.
__device__ __forceinline__ void lds_barrier() {
    asm volatile("s_waitcnt lgkmcnt(0)\n\ts_barrier" ::: "memory");
}

// Denominator block: 256 threads = 4 waves. Wave w owns rows [64w, 64w+64)
// as 4 M-tiles of 16. Lane l: q=l>>4, b=l&15 (batch column).
// E=exp(trans) bf16 persistent in VGPRs (4x8 short8 = 128 VGPR/lane).
// V (16 cols x 256 states bf16) double-buffered in LDS, XOR-swizzled:
//   element (col b, state k) at short index b*256 + (((k>>3)^(b&7))<<3) + (k&7)
// -> ds_read_b128 bank-group = ((4kt+q)^(b&7)): 2-way max (free).
// Normalization: stats produced at t%4==0 steps, consumed (exact pow2 rescale)
// at t%4==1 -> exactly one barrier per step, reduce off critical path.
__global__ __launch_bounds__(256, 1) void crf_kernel(
    const float* __restrict__ inputs, const float* __restrict__ trans,
    const int* __restrict__ tags, const int* __restrict__ mask,
    float* __restrict__ out)
{
    __shared__ __align__(16) short Vlds[2][GCOLS * 256];   // 16 KB
    __shared__ __align__(16) float mbuf[GCOLS * 16];
    __shared__ __align__(16) float sbuf[GCOLS * 16];
    __shared__ float nred[4];
    __shared__ int   nredi[4];

    if (blockIdx.x >= NDB) {
        // ---------------- numerator path: one batch per block ----------------
        const int bb = blockIdx.x - NDB;
        float part = 0.f; int ms = 0;
        #pragma unroll
        for (int h = 0; h < 2; ++h) {
            const int t = threadIdx.x + 256 * h;
            const int tg = tags[bb * T_ + t];
            const float fm = (float)mask[bb * T_ + t];
            if (t >= 1)      part += trans[tg * N_ + tags[bb * T_ + t - 1]] * fm;
            if (t <= T_ - 2) part += inputs[((size_t)bb * T_ + t) * N_ + tg] * fm;
            ms += mask[bb * T_ + t];
        }
        #pragma unroll
        for (int off = 1; off < 64; off <<= 1) {
            part += __shfl_xor(part, off, 64);
            ms   += __shfl_xor(ms, off, 64);
        }
        const int t0 = threadIdx.x;
        if ((t0 & 63) == 0) { nred[t0 >> 6] = part; nredi[t0 >> 6] = ms; }
        __syncthreads();
        if (t0 == 0) {
            float tot = 0.f; int mtot = 0;
            for (int i = 0; i < 4; ++i) { tot += nred[i]; mtot += nredi[i]; }
            tot += trans[tags[bb * T_] * N_ + START_];
            const int last = mtot - 1;
            const int lt = tags[bb * T_ + last];
            tot += trans[STOP_ * N_ + lt]
                 + inputs[((size_t)bb * T_ + (T_ - 1)) * N_ + lt]
                   * (float)mask[bb * T_ + T_ - 1];
            atomicAdd(out, tot);
        }
        return;
    }

    // ---------------- denominator path ----------------
    const int tid = threadIdx.x;
    const int w = tid >> 6;          // wave 0..3
    const int l = tid & 63;
    const int q = l >> 4;            // quad 0..3
    const int b = l & 15;            // batch column
    const int bsw = b & 7;
    const int bg = blockIdx.x * GCOLS + b;
    const int vrow = b * 256;        // short index of this column's V row

    // ---- persistent A-fragments: lane holds E[64w+16mt+b][32kt+8q+jj]
    short8 afrag[4][8];
    #pragma unroll
    for (int mt = 0; mt < 4; ++mt) {
        const int row = 64 * w + 16 * mt + b;
        #pragma unroll
        for (int kt = 0; kt < 8; ++kt) {
            const float* p = trans + row * N_ + kt * 32 + q * 8;
            floatx4 t0 = *(const floatx4*)p;
            floatx4 t1 = *(const floatx4*)(p + 4);
            short8 a;
            a[0] = f2bf(__builtin_amdgcn_exp2f(t0[0] * LOG2E));
            a[1] = f2bf(__builtin_amdgcn_exp2f(t0[1] * LOG2E));
            a[2] = f2bf(__builtin_amdgcn_exp2f(t0[2] * LOG2E));
            a[3] = f2bf(__builtin_amdgcn_exp2f(t0[3] * LOG2E));
            a[4] = f2bf(__builtin_amdgcn_exp2f(t1[0] * LOG2E));
            a[5] = f2bf(__builtin_amdgcn_exp2f(t1[1] * LOG2E));
            a[6] = f2bf(__builtin_amdgcn_exp2f(t1[2] * LOG2E));
            a[7] = f2bf(__builtin_amdgcn_exp2f(t1[3] * LOG2E));
            afrag[mt][kt] = a;
        }
    }

    const float* emitp = inputs + (size_t)bg * T_ * N_;
    const int*   maskp = mask + bg * T_;
    const int eoff = 64 * w + 4 * q;        // + 16*mt for each tile
    float C = 0.f;
    float colsum = 0.f;                      // only consumed if mask==0 (ones here)
    float u[4][4];
    int ph = 0;

    auto writeV = [&](int p) {
        #pragma unroll
        for (int mt = 0; mt < 4; ++mt) {
            const int g = 8 * w + 2 * mt + (q >> 1);
            short4_t vv;
            #pragma unroll
            for (int r = 0; r < 4; ++r) vv[r] = f2bf_fast(u[mt][r]);
            *(short4_t*)&Vlds[p][vrow + ((g ^ bsw) << 3) + 4 * (q & 1)] = vv;
        }
    };
    auto writeStats = [&]() {
        float mx = u[0][0], sm = 0.f;
        #pragma unroll
        for (int mt = 0; mt < 4; ++mt)
            #pragma unroll
            for (int r = 0; r < 4; ++r) { mx = fmaxf(mx, u[mt][r]); sm += u[mt][r]; }
        mbuf[b * 16 + w * 4 + q] = mx;
        sbuf[b * 16 + w * 4 + q] = sm;
    };

    // ---- init t=0: u0 = exp(trans[:,START] + emit0); produce stats; write V0
    #pragma unroll
    for (int mt = 0; mt < 4; ++mt) {
        floatx4 em = *(const floatx4*)(emitp + eoff + 16 * mt);
        #pragma unroll
        for (int r = 0; r < 4; ++r) {
            const int j = eoff + 16 * mt + r;
            u[mt][r] = __builtin_amdgcn_exp2f((trans[j * N_ + START_] + em[r]) * LOG2E);
        }
    }
    writeStats();
    writeV(0);
    lds_barrier();

    // ---- pipeline state: xp = exp(emit(t)), eN = raw emit(t+1); masks
    floatx4 xp[4], eN[4];
    #pragma unroll
    for (int mt = 0; mt < 4; ++mt) {
        floatx4 e1 = *(const floatx4*)(emitp + N_ + eoff + 16 * mt);
        #pragma unroll
        for (int r = 0; r < 4; ++r) xp[mt][r] = __builtin_amdgcn_exp2f(e1[r] * LOG2E);
        eN[mt] = *(const floatx4*)(emitp + 2 * (size_t)N_ + eoff + 16 * mt);
    }
    float mA = (float)maskp[0];
    float mN = (float)maskp[1];

    auto body = [&](int t, bool produce, bool consume) {
        const int tp = (t + 2 <= T_ - 1) ? t + 2 : T_ - 1;
        floatx4 eF[4];
        #pragma unroll
        for (int mt = 0; mt < 4; ++mt)
            eF[mt] = *(const floatx4*)(emitp + (size_t)tp * N_ + eoff + 16 * mt);
        const float mF = (float)maskp[tp - 1];

        // B fragments (swizzled, 2-way max conflicts)
        short8 bfrag[8];
        #pragma unroll
        for (int kt = 0; kt < 8; ++kt)
            bfrag[kt] = *(const short8*)&Vlds[ph][vrow + ((((kt << 2) + q) ^ bsw) << 3)];

        // consume: lagged cross-wave max -> exact pow2 rescale (hidden under MFMA)
        float rs = 1.f; float dC = 0.f;
        if (consume) {
            floatx4 m0 = *(const floatx4*)&mbuf[b * 16];
            floatx4 m1 = *(const floatx4*)&mbuf[b * 16 + 4];
            floatx4 m2 = *(const floatx4*)&mbuf[b * 16 + 8];
            floatx4 m3 = *(const floatx4*)&mbuf[b * 16 + 12];
            float cmax = fmaxf(fmaxf(fmaxf(m0[0], m0[1]), fmaxf(m0[2], m0[3])),
                               fmaxf(fmaxf(m1[0], m1[1]), fmaxf(m1[2], m1[3])));
            cmax = fmaxf(cmax,
                   fmaxf(fmaxf(fmaxf(m2[0], m2[1]), fmaxf(m2[2], m2[3])),
                         fmaxf(fmaxf(m3[0], m3[1]), fmaxf(m3[2], m3[3]))));
            floatx4 s0 = *(const floatx4*)&sbuf[b * 16];
            floatx4 s1 = *(const floatx4*)&sbuf[b * 16 + 4];
            floatx4 s2 = *(const floatx4*)&sbuf[b * 16 + 8];
            floatx4 s3 = *(const floatx4*)&sbuf[b * 16 + 12];
            float csum = ((s0[0]+s0[1])+(s0[2]+s0[3])) + ((s1[0]+s1[1])+(s1[2]+s1[3]))
                       + ((s2[0]+s2[1])+(s2[2]+s2[3])) + ((s3[0]+s3[1])+(s3[2]+s3[3]));
            const uint32_t cb = __builtin_bit_cast(uint32_t, cmax);
            const int eb = (int)((cb >> 23) & 0xFFu);
            rs = __builtin_bit_cast(float, (uint32_t)(253 - eb) << 23);  // 2^(126-eb)
            dC = (float)(eb - 126);
            colsum = csum * rs;
        }

        // exp(emit(t+1)) for next step (off critical path)
        floatx4 xpN[4];
        #pragma unroll
        for (int mt = 0; mt < 4; ++mt)
            #pragma unroll
            for (int r = 0; r < 4; ++r)
                xpN[mt][r] = __builtin_amdgcn_exp2f(eN[mt][r] * LOG2E);

        floatx4 acc[4] = {{0.f,0.f,0.f,0.f},{0.f,0.f,0.f,0.f},
                          {0.f,0.f,0.f,0.f},{0.f,0.f,0.f,0.f}};
        #pragma unroll
        for (int kt = 0; kt < 8; ++kt)
            #pragma unroll
            for (int mt = 0; mt < 4; ++mt)
                acc[mt] = __builtin_amdgcn_mfma_f32_16x16x32_bf16(
                              afrag[mt][kt], bfrag[kt], acc[mt], 0, 0, 0);

        const bool live = (mA != 0.f);
        #pragma unroll
        for (int mt = 0; mt < 4; ++mt)
            #pragma unroll
            for (int r = 0; r < 4; ++r)
                u[mt][r] = live ? acc[mt][r] * xp[mt][r] : colsum;
        if (consume) {
            C += dC;
            #pragma unroll
            for (int mt = 0; mt < 4; ++mt)
                #pragma unroll
                for (int r = 0; r < 4; ++r) u[mt][r] *= rs;
        }
        writeV(ph ^ 1);
        if (produce) writeStats();
        lds_barrier();
        ph ^= 1;
        #pragma unroll
        for (int mt = 0; mt < 4; ++mt) { xp[mt] = xpN[mt]; eN[mt] = eF[mt]; }
        mA = mN; mN = mF;
    };

    // t = 1..511; produce at t%4==0 (incl. t=0 init), consume at t%4==1
    for (int g = 0; g < 127; ++g) {
        const int t = 4 * g + 1;
        body(t,     false, true);
        body(t + 1, false, false);
        body(t + 2, false, false);
        body(t + 3, true,  false);
    }
    body(509, false, true);
    body(510, false, false);
    body(511, false, false);

    // ---- final: denom = ln2 * (C + log2(sum_j u[j]*2^(trans[STOP,j]*log2e)))
    float fin = 0.f;
    #pragma unroll
    for (int mt = 0; mt < 4; ++mt) {
        floatx4 st = *(const floatx4*)(trans + STOP_ * N_ + eoff + 16 * mt);
        #pragma unroll
        for (int r = 0; r < 4; ++r)
            fin += u[mt][r] * __builtin_amdgcn_exp2f(st[r] * LOG2E);
    }
    fin += __shfl_xor(fin, 16, 64);
    fin += __shfl_xor(fin, 32, 64);
    if (l < 16) sbuf[b * 16 + w] = fin;
    __syncthreads();
    if (tid < 16) {           // b == tid, w == 0: C is this column's offset
        float tot = sbuf[tid * 16] + sbuf[tid * 16 + 1]
                  + sbuf[tid * 16 + 2] + sbuf[tid * 16 + 3];
        const float denom = (C + __builtin_amdgcn_logf(tot)) * LN2;
        atomicAdd(out, -denom);
    }
}

extern "C" void kernel_launch(void* const* d_in, const int* in_sizes, int n_in,
                              void* d_out, int out_size, void* d_ws, size_t ws_size,
                              hipStream_t stream) {
    const float* inputs = (const float*)d_in[0];
    const float* trans  = (const float*)d_in[1];
    const int*   tags   = (const int*)d_in[2];
    const int*   mask   = (const int*)d_in[3];
    float* out = (float*)d_out;
    hipMemsetAsync(out, 0, sizeof(float), stream);
    dim3 grid(NDB + B_);     // 16 denominator blocks + 256 numerator blocks
    dim3 block(256);
    crf_kernel<<<grid, block, 0, stream>>>(inputs, trans, tags, mask, out);
}

// Round 4
// 502.400 us; speedup vs baseline: 1.5539x; 1.5539x over previous
//
#include <hip/hip_runtime.h>
#include <hip/hip_bf16.h>
#include <stdint.h>

#define B_    256
#define T_    512
#define N_    256
#define START_ 254
#define STOP_  255
#define GCOLS 16
#define NF    16          // forward denominator blocks
#define ND    32          // total denominator blocks (16 fwd + 16 bwd)
#define LOG2E 1.4426950408889634f
#define LN2   0.6931471805599453f
#define VPITCH 264        // shorts per V row (round-2 layout; swizzle measured worse)

// d_ws float layout: [0,65536) alphaF, [65536,131072) betaB, [131072,131328) CF, [131328,131584) CB
#define WSB_OFF 65536
#define WCF_OFF 131072
#define WCB_OFF 131328

typedef __attribute__((ext_vector_type(8))) short short8;
typedef __attribute__((ext_vector_type(4))) short short4_t;
typedef __attribute__((ext_vector_type(4))) float floatx4;

__device__ __forceinline__ short f2bf(float f) {        // RNE (one-time E build)
    uint32_t u = __builtin_bit_cast(uint32_t, f);
    u = (u + 0x7FFFu + ((u >> 16) & 1u)) >> 16;
    return (short)(uint16_t)u;
}
__device__ __forceinline__ short f2bf_fast(float f) {   // round-half-up (per step)
    uint32_t u = __builtin_bit_cast(uint32_t, f);
    return (short)((u + 0x8000u) >> 16);
}

// lgkm-only barrier: LDS drained, global prefetch stays in flight.
__device__ __forceinline__ void lds_barrier() {
    asm volatile("s_waitcnt lgkmcnt(0)\n\ts_barrier" ::: "memory");
}

struct DenomShared {
    short V[2][GCOLS * VPITCH];   // double-buffered, 16.9 KB
    float mbuf[GCOLS * 8];
    float sbuf[GCOLS * 8];
};

// 512 threads = 8 waves; wave w owns rows [32w,32w+32) as 2 M-tiles.
// Lane l: q=l>>4, b=l&15 (batch column). ISF: forward chain alpha(1..256).
// !ISF: backward chain beta(510..256) via E^T; xp multiplies the *input* vector
// (applied at V-write). Lagged pow2 normalization (produce s%4==0, consume s%4==1).
template<bool ISF>
__device__ __forceinline__ void denom_path(
    DenomShared& sh, const float* __restrict__ inputs,
    const float* __restrict__ trans, const int* __restrict__ mask,
    float* __restrict__ ws, int blkLocal)
{
    const int tid = threadIdx.x;
    const int w = tid >> 6;
    const int l = tid & 63;
    const int q = l >> 4;
    const int b = l & 15;
    const int bg = blkLocal * GCOLS + b;
    const int j0 = 32 * w + 4 * q;          // + 16*mt
    const int vrow = b * VPITCH;
    const int S = ISF ? 256 : 255;          // serial steps after init

    // ---- persistent A-fragments: fwd A=E, bwd A=E^T  (rows 32w+16mt+b)
    short8 afrag[2][8];
    #pragma unroll
    for (int mt = 0; mt < 2; ++mt) {
        const int row = 32 * w + 16 * mt + b;
        #pragma unroll
        for (int kt = 0; kt < 8; ++kt) {
            short8 a;
            if (ISF) {
                const float* p = trans + row * N_ + kt * 32 + q * 8;
                floatx4 t0 = *(const floatx4*)p;
                floatx4 t1 = *(const floatx4*)(p + 4);
                a[0] = f2bf(__builtin_amdgcn_exp2f(t0[0] * LOG2E));
                a[1] = f2bf(__builtin_amdgcn_exp2f(t0[1] * LOG2E));
                a[2] = f2bf(__builtin_amdgcn_exp2f(t0[2] * LOG2E));
                a[3] = f2bf(__builtin_amdgcn_exp2f(t0[3] * LOG2E));
                a[4] = f2bf(__builtin_amdgcn_exp2f(t1[0] * LOG2E));
                a[5] = f2bf(__builtin_amdgcn_exp2f(t1[1] * LOG2E));
                a[6] = f2bf(__builtin_amdgcn_exp2f(t1[2] * LOG2E));
                a[7] = f2bf(__builtin_amdgcn_exp2f(t1[3] * LOG2E));
            } else {
                #pragma unroll
                for (int jj = 0; jj < 8; ++jj) {
                    const int k = kt * 32 + q * 8 + jj;
                    a[jj] = f2bf(__builtin_amdgcn_exp2f(trans[k * N_ + row] * LOG2E));
                }
            }
            afrag[mt][kt] = a;
        }
    }

    const float* emitp = inputs + (size_t)bg * T_ * N_;
    const int*   maskp = mask + bg * T_;
    float C = 0.f;
    float colsum = 0.f;
    float u[2][4];
    int ph = 0;

    // emit index for step s; mask index for step s
    auto EIDX = [&](int s) { return ISF ? s : (511 - s); };
    auto MIDX = [&](int s) { return ISF ? (s - 1) : (511 - s); };

    floatx4 xp[2];          // exp(emit(EIDX(s))) for the current step
    floatx4 eBuf[4][2];     // raw emit rotation: slot s&3 holds emit(EIDX(s+3))
    float   mBufR[4];       // mask rotation: slot s&3 holds mask(MIDX(s+3))

    auto loadE = [&](int s, floatx4* dst) {
        const size_t off = (size_t)EIDX(s) * N_ + j0;
        dst[0] = *(const floatx4*)(emitp + off);
        dst[1] = *(const floatx4*)(emitp + off + 16);
    };

    auto writeV = [&](int p) {     // fwd: V=u ; bwd: V=u*xp
        #pragma unroll
        for (int mt = 0; mt < 2; ++mt) {
            short4_t vv;
            #pragma unroll
            for (int r = 0; r < 4; ++r)
                vv[r] = f2bf_fast(ISF ? u[mt][r] : u[mt][r] * xp[mt][r]);
            *(short4_t*)&sh.V[p][vrow + j0 + 16 * mt] = vv;
        }
    };
    auto writeStats = [&]() {
        float mx = u[0][0], sm = 0.f;
        #pragma unroll
        for (int mt = 0; mt < 2; ++mt)
            #pragma unroll
            for (int r = 0; r < 4; ++r) { mx = fmaxf(mx, u[mt][r]); sm += u[mt][r]; }
        mx = fmaxf(mx, __shfl_xor(mx, 16, 64)); sm += __shfl_xor(sm, 16, 64);
        mx = fmaxf(mx, __shfl_xor(mx, 32, 64)); sm += __shfl_xor(sm, 32, 64);
        if (l < 16) { sh.mbuf[b * 8 + w] = mx; sh.sbuf[b * 8 + w] = sm; }
    };

    // ---- init (s=0): fwd u=exp(trans[:,START]+emit0); bwd u=exp(trans[STOP,:])
    if (ISF) {
        #pragma unroll
        for (int mt = 0; mt < 2; ++mt) {
            floatx4 em = *(const floatx4*)(emitp + j0 + 16 * mt);
            #pragma unroll
            for (int r = 0; r < 4; ++r) {
                const int j = j0 + 16 * mt + r;
                u[mt][r] = __builtin_amdgcn_exp2f((trans[j * N_ + START_] + em[r]) * LOG2E);
            }
        }
    } else {
        #pragma unroll
        for (int mt = 0; mt < 2; ++mt) {
            floatx4 st = *(const floatx4*)(trans + STOP_ * N_ + j0 + 16 * mt);
            #pragma unroll
            for (int r = 0; r < 4; ++r)
                u[mt][r] = __builtin_amdgcn_exp2f(st[r] * LOG2E);
        }
    }
    // xp for s=1 (bwd init-write also needs exp(emit(511)) = xp slot of s=... handled below)
    {
        floatx4 e1[2];
        if (!ISF) {          // bwd V_1 = u * exp(emit(511)); EIDX(0)=511
            loadE(0, e1);
            #pragma unroll
            for (int mt = 0; mt < 2; ++mt)
                #pragma unroll
                for (int r = 0; r < 4; ++r)
                    xp[mt][r] = __builtin_amdgcn_exp2f(e1[mt][r] * LOG2E);
        }
        writeStats();
        writeV(0);
        if (!ISF) { }        // bwd xp gets replaced below for s=1
        loadE(1, e1);        // xp for step 1
        floatx4 tmp0 = e1[0], tmp1 = e1[1];
        loadE(2, eBuf[3]);   // slot (1-2)&3=3 holds EIDX(2) -> xpN at body(1)
        loadE(3, eBuf[0]);   // slot (2-2)&3=0 holds EIDX(3) -> xpN at body(2)
        mBufR[2] = (float)maskp[MIDX(1)];   // slot (1+1)&3
        mBufR[3] = (float)maskp[MIDX(2)];
        mBufR[0] = (float)maskp[MIDX(3)];
        #pragma unroll
        for (int r = 0; r < 4; ++r) {
            xp[0][r] = __builtin_amdgcn_exp2f(tmp0[r] * LOG2E);
            xp[1][r] = __builtin_amdgcn_exp2f(tmp1[r] * LOG2E);
        }
    }
    lds_barrier();

    // body: slotLoad=s&3 (loads EIDX(s+3), MIDX(s+3)); xpN from slot (s+2)&3; mA from slot (s+1)&3
    auto body = [&](int s, int slotLoad, int slotXp, int slotMask,
                    bool produce, bool consume) {
        loadE(s + 3, eBuf[slotLoad]);
        mBufR[slotLoad] = (float)maskp[MIDX(s + 3)];
        const float mA = mBufR[slotMask];

        short8 bfrag[8];
        #pragma unroll
        for (int kt = 0; kt < 8; ++kt)
            bfrag[kt] = *(const short8*)&sh.V[ph][vrow + kt * 32 + q * 8];

        // consume lagged stats -> exact pow2 rescale (hidden under MFMA wait)
        float rs = 1.f, dC = 0.f;
        if (consume) {
            floatx4 m0 = *(const floatx4*)&sh.mbuf[b * 8];
            floatx4 m1 = *(const floatx4*)&sh.mbuf[b * 8 + 4];
            floatx4 s0 = *(const floatx4*)&sh.sbuf[b * 8];
            floatx4 s1 = *(const floatx4*)&sh.sbuf[b * 8 + 4];
            float cmax = fmaxf(fmaxf(fmaxf(m0[0], m0[1]), fmaxf(m0[2], m0[3])),
                               fmaxf(fmaxf(m1[0], m1[1]), fmaxf(m1[2], m1[3])));
            float csum = ((s0[0] + s0[1]) + (s0[2] + s0[3])) +
                         ((s1[0] + s1[1]) + (s1[2] + s1[3]));
            const uint32_t cb = __builtin_bit_cast(uint32_t, cmax);
            const int eb = (int)((cb >> 23) & 0xFFu);
            rs = __builtin_bit_cast(float, (uint32_t)(253 - eb) << 23);  // 2^(126-eb)
            dC = (float)(eb - 126);
            colsum = csum * rs;
        }

        // xp for next step (off critical path)
        floatx4 xpN[2];
        #pragma unroll
        for (int mt = 0; mt < 2; ++mt)
            #pragma unroll
            for (int r = 0; r < 4; ++r)
                xpN[mt][r] = __builtin_amdgcn_exp2f(eBuf[slotXp][mt][r] * LOG2E);

        floatx4 a0 = {0.f,0.f,0.f,0.f}, a1 = {0.f,0.f,0.f,0.f};
        floatx4 a2 = {0.f,0.f,0.f,0.f}, a3 = {0.f,0.f,0.f,0.f};
        #pragma unroll
        for (int kt = 0; kt < 4; ++kt) {   // two 4-deep half-chains per M-tile
            a0 = __builtin_amdgcn_mfma_f32_16x16x32_bf16(afrag[0][kt],     bfrag[kt],     a0, 0, 0, 0);
            a1 = __builtin_amdgcn_mfma_f32_16x16x32_bf16(afrag[0][kt + 4], bfrag[kt + 4], a1, 0, 0, 0);
            a2 = __builtin_amdgcn_mfma_f32_16x16x32_bf16(afrag[1][kt],     bfrag[kt],     a2, 0, 0, 0);
            a3 = __builtin_amdgcn_mfma_f32_16x16x32_bf16(afrag[1][kt + 4], bfrag[kt + 4], a3, 0, 0, 0);
        }

        const bool live = (mA != 0.f);
        #pragma unroll
        for (int r = 0; r < 4; ++r) {
            const float v0 = a0[r] + a1[r], v1 = a2[r] + a3[r];
            u[0][r] = live ? (ISF ? v0 * xp[0][r] : v0) : colsum;
            u[1][r] = live ? (ISF ? v1 * xp[1][r] : v1) : colsum;
        }
        if (consume) {
            C += dC;
            #pragma unroll
            for (int mt = 0; mt < 2; ++mt)
                #pragma unroll
                for (int r = 0; r < 4; ++r) u[mt][r] *= rs;
        }
        if (produce) writeStats();
        writeV(ph ^ 1);
        lds_barrier();
        ph ^= 1;
        xp[0] = xpN[0]; xp[1] = xpN[1];
    };

    // steps s=1..S; produce at s%4==0 (incl. init), consume at s%4==1
    const int ngrp = S / 4;              // fwd 64, bwd 63
    #pragma unroll 1
    for (int g = 0; g < ngrp; ++g) {
        const int s = 4 * g + 1;
        body(s,     1, 3, 2, false, true);
        body(s + 1, 2, 0, 3, false, false);
        body(s + 2, 3, 1, 0, false, false);
        body(s + 3, 0, 2, 1, true,  false);
    }
    if (!ISF) {   // bwd tail s=253,254,255
        body(253, 1, 3, 2, false, true);
        body(254, 2, 0, 3, false, false);
        body(255, 3, 1, 0, false, false);
    }

    // ---- store partials: u = alpha(256) (fwd) / beta(256) (bwd), scale 2^-C
    float* wsV = ws + (ISF ? 0 : WSB_OFF);
    #pragma unroll
    for (int mt = 0; mt < 2; ++mt) {
        floatx4 vv = {u[mt][0], u[mt][1], u[mt][2], u[mt][3]};
        *(floatx4*)&wsV[(size_t)bg * N_ + j0 + 16 * mt] = vv;
    }
    if (tid < 16) {
        float* wsC = ws + (ISF ? WCF_OFF : WCB_OFF);
        wsC[blkLocal * GCOLS + tid] = C;
    }
}

__global__ __launch_bounds__(512, 2) void crf_main(
    const float* __restrict__ inputs, const float* __restrict__ trans,
    const int* __restrict__ tags, const int* __restrict__ mask,
    float* __restrict__ out, float* __restrict__ ws)
{
    __shared__ DenomShared sh;

    if (blockIdx.x >= ND) {
        // ---------------- numerator: one batch per block ----------------
        float* nred = sh.mbuf;
        int*   nredi = (int*)sh.sbuf;
        const int bb = blockIdx.x - ND;
        const int t  = threadIdx.x;            // 0..511
        const int tg = tags[bb * T_ + t];
        const float fm = (float)mask[bb * T_ + t];
        float part = 0.f;
        if (t >= 1)      part += trans[tg * N_ + tags[bb * T_ + t - 1]] * fm;
        if (t <= T_ - 2) part += inputs[((size_t)bb * T_ + t) * N_ + tg] * fm;
        int ms = mask[bb * T_ + t];
        #pragma unroll
        for (int off = 1; off < 64; off <<= 1) {
            part += __shfl_xor(part, off, 64);
            ms   += __shfl_xor(ms, off, 64);
        }
        if ((t & 63) == 0) { nred[t >> 6] = part; nredi[t >> 6] = ms; }
        __syncthreads();
        if (t == 0) {
            float tot = 0.f; int mtot = 0;
            for (int i = 0; i < 8; ++i) { tot += nred[i]; mtot += nredi[i]; }
            tot += trans[tags[bb * T_] * N_ + START_];
            const int last = mtot - 1;
            const int lt = tags[bb * T_ + last];
            tot += trans[STOP_ * N_ + lt]
                 + inputs[((size_t)bb * T_ + (T_ - 1)) * N_ + lt]
                   * (float)mask[bb * T_ + T_ - 1];
            atomicAdd(out, tot);
        }
        return;
    }

    if (blockIdx.x < NF) denom_path<true>(sh, inputs, trans, mask, ws, blockIdx.x);
    else                 denom_path<false>(sh, inputs, trans, mask, ws, blockIdx.x - NF);
}

// denom_b = LN2 * (CF_b + CB_b + log2(sum_j alphaF[b][j] * betaB[b][j]))
__global__ __launch_bounds__(256) void crf_combine(
    const float* __restrict__ ws, float* __restrict__ out)
{
    __shared__ float red[4];
    const int bb = blockIdx.x;
    const int t = threadIdx.x;
    float p = ws[(size_t)bb * N_ + t] * ws[WSB_OFF + (size_t)bb * N_ + t];
    #pragma unroll
    for (int off = 1; off < 64; off <<= 1) p += __shfl_xor(p, off, 64);
    if ((t & 63) == 0) red[t >> 6] = p;
    __syncthreads();
    if (t == 0) {
        const float tot = red[0] + red[1] + red[2] + red[3];
        const float denom = (ws[WCF_OFF + bb] + ws[WCB_OFF + bb]
                             + __builtin_amdgcn_logf(tot)) * LN2;
        atomicAdd(out, -denom);
    }
}

extern "C" void kernel_launch(void* const* d_in, const int* in_sizes, int n_in,
                              void* d_out, int out_size, void* d_ws, size_t ws_size,
                              hipStream_t stream) {
    const float* inputs = (const float*)d_in[0];
    const float* trans  = (const float*)d_in[1];
    const int*   tags   = (const int*)d_in[2];
    const int*   mask   = (const int*)d_in[3];
    float* out = (float*)d_out;
    float* ws  = (float*)d_ws;
    hipMemsetAsync(out, 0, sizeof(float), stream);
    crf_main<<<dim3(ND + B_), dim3(512), 0, stream>>>(inputs, trans, tags, mask, out, ws);
    crf_combine<<<dim3(B_), dim3(256), 0, stream>>>(ws, out);
}

// Round 5
// 394.182 us; speedup vs baseline: 1.9805x; 1.2745x over previous
//
#include <hip/hip_runtime.h>
#include <hip/hip_bf16.h>
#include <stdint.h>

#define B_    256
#define T_    512
#define N_    256
#define START_ 254
#define STOP_  255
#define GCOLS 16
#define NF    16          // forward denominator blocks
#define ND    32          // total denominator blocks (16 fwd + 16 bwd)
#define LOG2E 1.4426950408889634f
#define LN2   0.6931471805599453f
#define VP8   272         // bytes per V column row (256 + 16 pad -> 2-way banks only)

// d_ws float layout: [0,65536) alphaF, [65536,131072) betaB, [131072,131328) CF, [131328,131584) CB
#define WSB_OFF 65536
#define WCF_OFF 131072
#define WCB_OFF 131328

typedef __attribute__((ext_vector_type(4))) float floatx4;

__device__ __forceinline__ void lds_barrier() {
    asm volatile("s_waitcnt lgkmcnt(0)\n\ts_barrier" ::: "memory");
}

__device__ __forceinline__ int pk_fp8x4(float a, float b, float c, float d) {  // e4m3
    int r = __builtin_amdgcn_cvt_pk_fp8_f32(a, b, 0, false);
    return __builtin_amdgcn_cvt_pk_fp8_f32(c, d, r, true);
}
__device__ __forceinline__ int pk_bf8x4(float a, float b, float c, float d) {  // e5m2
    int r = __builtin_amdgcn_cvt_pk_bf8_f32(a, b, 0, false);
    return __builtin_amdgcn_cvt_pk_bf8_f32(c, d, r, true);
}
__device__ __forceinline__ long long mk64(int lo, int hi) {
    return ((long long)(unsigned long long)(unsigned)hi << 32) | (unsigned)lo;
}

struct DenomShared {
    alignas(16) char V[2][GCOLS * VP8];    // double-buffered V, e5m2, 8.7 KB
    alignas(16) float mbuf[GCOLS * 8];     // per-(col,wave) max
    alignas(16) float sbuf[GCOLS * 8];     // per-(col,wave) sum
};

// 512 threads = 8 waves; wave w owns rows [32w,32w+32) as 2 M-tiles.
// Lane l: q=l>>4, b=l&15 (batch column). A = E (e4m3, fwd) / E^T (bwd),
// persistent in VGPRs. B = V (e5m2) double-buffered in LDS.
// Lag-1 pow2 normalization: stats produced every step, consumed next step
// through the same single lgkm barrier. Rescale targets max in [2^-5,2^-4):
// written V <= 2^12.6 < bf8 max 2^15.8; floor ~2^-18 > 0 via e5m2 subnorms.
template<bool ISF>
__device__ __forceinline__ void denom_path(
    DenomShared& sh, const float* __restrict__ inputs,
    const float* __restrict__ trans, const int* __restrict__ mask,
    float* __restrict__ ws, int blkLocal)
{
    const int tid = threadIdx.x;
    const int w = tid >> 6;
    const int l = tid & 63;
    const int q = l >> 4;
    const int b = l & 15;
    const int bg = blkLocal * GCOLS + b;
    const int j0 = 32 * w + 4 * q;          // + 16*mt
    const int S = ISF ? 256 : 255;          // serial steps after init

    auto EIDX = [](int s) { return ISF ? s : (511 - s); };
    auto MIDX = [](int s) { return ISF ? (s - 1) : (511 - s); };

    // ---- persistent A-fragments (e4m3): fwd A=E, bwd A=E^T
    long long afrag[2][8];
    #pragma unroll
    for (int mt = 0; mt < 2; ++mt) {
        const int row = 32 * w + 16 * mt + b;
        #pragma unroll
        for (int kt = 0; kt < 8; ++kt) {
            float e[8];
            if (ISF) {
                const float* p = trans + row * N_ + kt * 32 + q * 8;
                floatx4 t0 = *(const floatx4*)p;
                floatx4 t1 = *(const floatx4*)(p + 4);
                #pragma unroll
                for (int jj = 0; jj < 4; ++jj) {
                    e[jj]     = __builtin_amdgcn_exp2f(t0[jj] * LOG2E);
                    e[jj + 4] = __builtin_amdgcn_exp2f(t1[jj] * LOG2E);
                }
            } else {
                #pragma unroll
                for (int jj = 0; jj < 8; ++jj) {
                    const int k = kt * 32 + q * 8 + jj;
                    e[jj] = __builtin_amdgcn_exp2f(trans[k * N_ + row] * LOG2E);
                }
            }
            afrag[mt][kt] = mk64(pk_fp8x4(e[0], e[1], e[2], e[3]),
                                 pk_fp8x4(e[4], e[5], e[6], e[7]));
        }
    }

    const float* emitp = inputs + (size_t)bg * T_ * N_;
    const int*   maskp = mask + bg * T_;
    float C = 0.f;
    float u[2][4];

    auto produce = [&]() {   // per-step stats (max & sum per column)
        float mx = u[0][0], sm = 0.f;
        #pragma unroll
        for (int mt = 0; mt < 2; ++mt)
            #pragma unroll
            for (int r = 0; r < 4; ++r) { mx = fmaxf(mx, u[mt][r]); sm += u[mt][r]; }
        mx = fmaxf(mx, __shfl_xor(mx, 16, 64)); sm += __shfl_xor(sm, 16, 64);
        mx = fmaxf(mx, __shfl_xor(mx, 32, 64)); sm += __shfl_xor(sm, 32, 64);
        if (l < 16) { sh.mbuf[b * 8 + w] = mx; sh.sbuf[b * 8 + w] = sm; }
    };

    // ---- init (s=0): fwd u=exp(trans[:,START]+emit0); bwd u=exp(trans[STOP,:])
    if (ISF) {
        #pragma unroll
        for (int mt = 0; mt < 2; ++mt) {
            floatx4 em = *(const floatx4*)(emitp + j0 + 16 * mt);
            #pragma unroll
            for (int r = 0; r < 4; ++r) {
                const int j = j0 + 16 * mt + r;
                u[mt][r] = __builtin_amdgcn_exp2f((trans[j * N_ + START_] + em[r]) * LOG2E);
            }
        }
    } else {
        #pragma unroll
        for (int mt = 0; mt < 2; ++mt) {
            floatx4 st = *(const floatx4*)(trans + STOP_ * N_ + j0 + 16 * mt);
            #pragma unroll
            for (int r = 0; r < 4; ++r)
                u[mt][r] = __builtin_amdgcn_exp2f(st[r] * LOG2E);
        }
    }
    {
        float xpi[2][4] = {{1.f,1.f,1.f,1.f},{1.f,1.f,1.f,1.f}};
        if (!ISF) {   // bwd V_0 = u * exp(emit(511)); EIDX(0)=511
            #pragma unroll
            for (int mt = 0; mt < 2; ++mt) {
                floatx4 e = *(const floatx4*)(emitp + (size_t)511 * N_ + j0 + 16 * mt);
                #pragma unroll
                for (int r = 0; r < 4; ++r)
                    xpi[mt][r] = __builtin_amdgcn_exp2f(e[r] * LOG2E);
            }
        }
        produce();
        #pragma unroll
        for (int mt = 0; mt < 2; ++mt)
            *(int*)&sh.V[0][b * VP8 + j0 + 16 * mt] =
                pk_bf8x4(u[mt][0] * xpi[mt][0], u[mt][1] * xpi[mt][1],
                         u[mt][2] * xpi[mt][2], u[mt][3] * xpi[mt][3]);
    }
    // prefetch: eA = raw emit(EIDX(1)), eB = raw emit(EIDX(2))
    floatx4 eA[2], eB[2];
    eA[0] = *(const floatx4*)(emitp + (size_t)EIDX(1) * N_ + j0);
    eA[1] = *(const floatx4*)(emitp + (size_t)EIDX(1) * N_ + j0 + 16);
    eB[0] = *(const floatx4*)(emitp + (size_t)EIDX(2) * N_ + j0);
    eB[1] = *(const floatx4*)(emitp + (size_t)EIDX(2) * N_ + j0 + 16);
    float mA = (float)maskp[MIDX(1)];
    float mB = (float)maskp[MIDX(2)];
    lds_barrier();

    auto body = [&](int s, int pr) {
        const int sp = (s + 2 <= S) ? s + 2 : S;   // distance-2 prefetch
        floatx4 eC0 = *(const floatx4*)(emitp + (size_t)EIDX(sp) * N_ + j0);
        floatx4 eC1 = *(const floatx4*)(emitp + (size_t)EIDX(sp) * N_ + j0 + 16);
        const float mC = (float)maskp[MIDX(sp)];

        // B fragments first (deepest LDS latency)
        const char* vb = &sh.V[pr][b * VP8];
        long long bf[8];
        #pragma unroll
        for (int kt = 0; kt < 8; ++kt)
            bf[kt] = *(const long long*)(vb + kt * 32 + q * 8);

        // consume lag-1 stats -> exact pow2 rescale
        floatx4 m0 = *(const floatx4*)&sh.mbuf[b * 8];
        floatx4 m1 = *(const floatx4*)&sh.mbuf[b * 8 + 4];
        floatx4 s0 = *(const floatx4*)&sh.sbuf[b * 8];
        floatx4 s1 = *(const floatx4*)&sh.sbuf[b * 8 + 4];
        const float cmax = fmaxf(fmaxf(fmaxf(m0[0], m0[1]), fmaxf(m0[2], m0[3])),
                                 fmaxf(fmaxf(m1[0], m1[1]), fmaxf(m1[2], m1[3])));
        const float csum = ((s0[0] + s0[1]) + (s0[2] + s0[3])) +
                           ((s1[0] + s1[1]) + (s1[2] + s1[3]));
        const uint32_t cb = __builtin_bit_cast(uint32_t, cmax);
        const int eb = (int)((cb >> 23) & 0xFFu);
        const float rs = __builtin_bit_cast(float, (uint32_t)(249 - eb) << 23); // 2^(122-eb)

        // xp = exp(emit(EIDX(s)))  (from eA, loaded 2 steps ago)
        float xpv[2][4];
        #pragma unroll
        for (int r = 0; r < 4; ++r) {
            xpv[0][r] = __builtin_amdgcn_exp2f(eA[0][r] * LOG2E);
            xpv[1][r] = __builtin_amdgcn_exp2f(eA[1][r] * LOG2E);
        }

        floatx4 a0 = {0.f,0.f,0.f,0.f}, a1 = {0.f,0.f,0.f,0.f};
        floatx4 a2 = {0.f,0.f,0.f,0.f}, a3 = {0.f,0.f,0.f,0.f};
        #pragma unroll
        for (int kt = 0; kt < 4; ++kt) {   // two 4-deep half-chains per M-tile
            a0 = __builtin_amdgcn_mfma_f32_16x16x32_fp8_bf8(afrag[0][kt],     bf[kt],     a0, 0, 0, 0);
            a1 = __builtin_amdgcn_mfma_f32_16x16x32_fp8_bf8(afrag[0][kt + 4], bf[kt + 4], a1, 0, 0, 0);
            a2 = __builtin_amdgcn_mfma_f32_16x16x32_fp8_bf8(afrag[1][kt],     bf[kt],     a2, 0, 0, 0);
            a3 = __builtin_amdgcn_mfma_f32_16x16x32_fp8_bf8(afrag[1][kt + 4], bf[kt + 4], a3, 0, 0, 0);
        }

        const bool live = (mA != 0.f);
        #pragma unroll
        for (int r = 0; r < 4; ++r) {
            const float v0 = a0[r] + a1[r], v1 = a2[r] + a3[r];
            u[0][r] = (live ? (ISF ? v0 * xpv[0][r] : v0) : csum) * rs;
            u[1][r] = (live ? (ISF ? v1 * xpv[1][r] : v1) : csum) * rs;
        }
        C += (float)(eb - 122);

        produce();
        // write V: fwd V=u ; bwd V=u*xp
        #pragma unroll
        for (int mt = 0; mt < 2; ++mt) {
            *(int*)&sh.V[pr ^ 1][b * VP8 + j0 + 16 * mt] = ISF
                ? pk_bf8x4(u[mt][0], u[mt][1], u[mt][2], u[mt][3])
                : pk_bf8x4(u[mt][0] * xpv[mt][0], u[mt][1] * xpv[mt][1],
                           u[mt][2] * xpv[mt][2], u[mt][3] * xpv[mt][3]);
        }
        lds_barrier();
        eA[0] = eB[0]; eA[1] = eB[1]; eB[0] = eC0; eB[1] = eC1;
        mA = mB; mB = mC;
    };

    #pragma unroll 1
    for (int g = 0; g < 127; ++g) { body(2 * g + 1, 0); body(2 * g + 2, 1); }
    if (ISF) { body(255, 0); body(256, 1); }
    else     { body(255, 0); }

    // ---- store partials: u = alpha(256) (fwd) / beta(256) (bwd), scale 2^-C
    float* wsV = ws + (ISF ? 0 : WSB_OFF);
    #pragma unroll
    for (int mt = 0; mt < 2; ++mt) {
        floatx4 vv = {u[mt][0], u[mt][1], u[mt][2], u[mt][3]};
        *(floatx4*)&wsV[(size_t)bg * N_ + j0 + 16 * mt] = vv;
    }
    if (tid < 16) {
        float* wsC = ws + (ISF ? WCF_OFF : WCB_OFF);
        wsC[blkLocal * GCOLS + tid] = C;
    }
}

__global__ __launch_bounds__(512, 2) void crf_main(
    const float* __restrict__ inputs, const float* __restrict__ trans,
    const int* __restrict__ tags, const int* __restrict__ mask,
    float* __restrict__ out, float* __restrict__ ws)
{
    __shared__ DenomShared sh;

    if (blockIdx.x >= ND) {
        // ---------------- numerator: one batch per block ----------------
        float* nred = sh.mbuf;
        int*   nredi = (int*)sh.sbuf;
        const int bb = blockIdx.x - ND;
        const int t  = threadIdx.x;            // 0..511
        const int tg = tags[bb * T_ + t];
        const float fm = (float)mask[bb * T_ + t];
        float part = 0.f;
        if (t >= 1)      part += trans[tg * N_ + tags[bb * T_ + t - 1]] * fm;
        if (t <= T_ - 2) part += inputs[((size_t)bb * T_ + t) * N_ + tg] * fm;
        int ms = mask[bb * T_ + t];
        #pragma unroll
        for (int off = 1; off < 64; off <<= 1) {
            part += __shfl_xor(part, off, 64);
            ms   += __shfl_xor(ms, off, 64);
        }
        if ((t & 63) == 0) { nred[t >> 6] = part; nredi[t >> 6] = ms; }
        __syncthreads();
        if (t == 0) {
            float tot = 0.f; int mtot = 0;
            for (int i = 0; i < 8; ++i) { tot += nred[i]; mtot += nredi[i]; }
            tot += trans[tags[bb * T_] * N_ + START_];
            const int last = mtot - 1;
            const int lt = tags[bb * T_ + last];
            tot += trans[STOP_ * N_ + lt]
                 + inputs[((size_t)bb * T_ + (T_ - 1)) * N_ + lt]
                   * (float)mask[bb * T_ + T_ - 1];
            atomicAdd(out, tot);
        }
        return;
    }

    if (blockIdx.x < NF) denom_path<true>(sh, inputs, trans, mask, ws, blockIdx.x);
    else                 denom_path<false>(sh, inputs, trans, mask, ws, blockIdx.x - NF);
}

// denom_b = LN2 * (CF_b + CB_b + log2(sum_j alphaF[b][j] * betaB[b][j]))
__global__ __launch_bounds__(256) void crf_combine(
    const float* __restrict__ ws, float* __restrict__ out)
{
    __shared__ float red[4];
    const int bb = blockIdx.x;
    const int t = threadIdx.x;
    float p = ws[(size_t)bb * N_ + t] * ws[WSB_OFF + (size_t)bb * N_ + t];
    #pragma unroll
    for (int off = 1; off < 64; off <<= 1) p += __shfl_xor(p, off, 64);
    if ((t & 63) == 0) red[t >> 6] = p;
    __syncthreads();
    if (t == 0) {
        const float tot = red[0] + red[1] + red[2] + red[3];
        const float denom = (ws[WCF_OFF + bb] + ws[WCB_OFF + bb]
                             + __builtin_amdgcn_logf(tot)) * LN2;
        atomicAdd(out, -denom);
    }
}

extern "C" void kernel_launch(void* const* d_in, const int* in_sizes, int n_in,
                              void* d_out, int out_size, void* d_ws, size_t ws_size,
                              hipStream_t stream) {
    const float* inputs = (const float*)d_in[0];
    const float* trans  = (const float*)d_in[1];
    const int*   tags   = (const int*)d_in[2];
    const int*   mask   = (const int*)d_in[3];
    float* out = (float*)d_out;
    float* ws  = (float*)d_ws;
    hipMemsetAsync(out, 0, sizeof(float), stream);
    crf_main<<<dim3(ND + B_), dim3(512), 0, stream>>>(inputs, trans, tags, mask, out, ws);
    crf_combine<<<dim3(B_), dim3(256), 0, stream>>>(ws, out);
}

// Round 6
// 374.848 us; speedup vs baseline: 2.0827x; 1.0516x over previous
//
#include <hip/hip_runtime.h>
#include <hip/hip_bf16.h>
#include <stdint.h>

#define B_    256
#define T_    512
#define N_    256
#define START_ 254
#define STOP_  255
#define GCOLS 16
#define NF    16          // forward denominator blocks
#define ND    32          // total denominator blocks (16 fwd + 16 bwd)
#define LOG2E 1.4426950408889634f
#define LN2   0.6931471805599453f

// d_ws float layout: [0,65536) alphaF, [65536,131072) betaB, [131072,131328) CF, [131328,131584) CB
#define WSB_OFF 65536
#define WCF_OFF 131072
#define WCB_OFF 131328

typedef __attribute__((ext_vector_type(4))) float floatx4;
typedef __attribute__((ext_vector_type(2))) long long llx2;

__device__ __forceinline__ void lds_barrier() {
    asm volatile("s_waitcnt lgkmcnt(0)\n\ts_barrier" ::: "memory");
}

__device__ __forceinline__ int pk_fp8x4(float a, float b, float c, float d) {  // e4m3
    int r = __builtin_amdgcn_cvt_pk_fp8_f32(a, b, 0, false);
    return __builtin_amdgcn_cvt_pk_fp8_f32(c, d, r, true);
}
__device__ __forceinline__ int pk_bf8x4(float a, float b, float c, float d) {  // e5m2
    int r = __builtin_amdgcn_cvt_pk_bf8_f32(a, b, 0, false);
    return __builtin_amdgcn_cvt_pk_bf8_f32(c, d, r, true);
}
__device__ __forceinline__ long long mk64(int lo, int hi) {
    return ((long long)(unsigned long long)(unsigned)hi << 32) | (unsigned)lo;
}

// V layout (per buffer, 4096 B): element (k, col b) at
//   (k>>6)*1024 + ((k>>3)&3)*256 + b*16 + ((k>>5)&1)*8 + (k&7)
// Read: lane l=(q*16+b) does ds_read_b128 at p*1024 + 16*l -> contiguous 1KB
// per wave per p (zero bank conflicts); low 8B = kt=2p, high 8B = kt=2p+1.
struct DenomShared {
    alignas(16) char  V[2][4096];
    alignas(16) float mbuf[GCOLS * 20];   // per-col stats, pitch 20 (2-way banks max)
    alignas(16) float sbuf[GCOLS * 20];
};

// 512 threads = 8 waves; wave w owns rows [32w,32w+32) as 2 M-tiles.
// Lane l: q=l>>4, b=l&15 (batch column). A = E (e4m3, fwd) / E^T (bwd),
// persistent in VGPRs. B = V (e5m2) double-buffered in LDS, lane-contiguous.
// Lag-1 pow2 normalization; rescale folded into the emit exponential (fwd).
template<bool ISF>
__device__ __forceinline__ void denom_path(
    DenomShared& sh, const float* __restrict__ inputs,
    const float* __restrict__ trans, const int* __restrict__ mask,
    float* __restrict__ ws, int blkLocal)
{
    const int tid = threadIdx.x;
    const int w = tid >> 6;
    const int l = tid & 63;
    const int q = l >> 4;
    const int b = l & 15;
    const int bg = blkLocal * GCOLS + b;
    const int j0 = 32 * w + 4 * q;          // + 16*mt
    const int S = ISF ? 256 : 255;          // serial steps after init

    auto EIDX = [](int s) { return ISF ? s : (511 - s); };
    auto MIDX = [](int s) { return ISF ? (s - 1) : (511 - s); };

    // write address for (mt): state j = 32w+16mt+4q+r, 4 bytes (r contiguous)
    const int wa0 = ((w >> 1) << 10) + ((q >> 1) << 8) + (b << 4)
                  + ((w & 1) << 3) + ((q & 1) << 2);
    // + mt*512  (2mt in the G field = mt<<9)
    const int rbase = l << 4;               // read base: p*1024 + 16*l

    // ---- persistent A-fragments (e4m3): fwd A=E, bwd A=E^T
    long long afrag[2][8];
    #pragma unroll
    for (int mt = 0; mt < 2; ++mt) {
        const int row = 32 * w + 16 * mt + b;
        #pragma unroll
        for (int kt = 0; kt < 8; ++kt) {
            float e[8];
            if (ISF) {
                const float* p = trans + row * N_ + kt * 32 + q * 8;
                floatx4 t0 = *(const floatx4*)p;
                floatx4 t1 = *(const floatx4*)(p + 4);
                #pragma unroll
                for (int jj = 0; jj < 4; ++jj) {
                    e[jj]     = __builtin_amdgcn_exp2f(t0[jj] * LOG2E);
                    e[jj + 4] = __builtin_amdgcn_exp2f(t1[jj] * LOG2E);
                }
            } else {
                #pragma unroll
                for (int jj = 0; jj < 8; ++jj) {
                    const int k = kt * 32 + q * 8 + jj;
                    e[jj] = __builtin_amdgcn_exp2f(trans[k * N_ + row] * LOG2E);
                }
            }
            afrag[mt][kt] = mk64(pk_fp8x4(e[0], e[1], e[2], e[3]),
                                 pk_fp8x4(e[4], e[5], e[6], e[7]));
        }
    }

    const float* emitp = inputs + (size_t)bg * T_ * N_;
    const int*   maskp = mask + bg * T_;
    float C = 0.f;
    float u[2][4];

    auto produce = [&]() {   // per-step stats; one shuffle, 2 partials/wave/col
        float mx = u[0][0], sm = 0.f;
        #pragma unroll
        for (int mt = 0; mt < 2; ++mt)
            #pragma unroll
            for (int r = 0; r < 4; ++r) { mx = fmaxf(mx, u[mt][r]); sm += u[mt][r]; }
        mx = fmaxf(mx, __shfl_xor(mx, 32, 64));
        sm += __shfl_xor(sm, 32, 64);
        if (l < 32) {
            const int idx = b * 20 + w * 2 + q;   // q in {0,1} here
            sh.mbuf[idx] = mx; sh.sbuf[idx] = sm;
        }
    };

    // ---- init (s=0): fwd u=exp(trans[:,START]+emit0); bwd u=exp(trans[STOP,:])
    if (ISF) {
        #pragma unroll
        for (int mt = 0; mt < 2; ++mt) {
            floatx4 em = *(const floatx4*)(emitp + j0 + 16 * mt);
            #pragma unroll
            for (int r = 0; r < 4; ++r) {
                const int j = j0 + 16 * mt + r;
                u[mt][r] = __builtin_amdgcn_exp2f((trans[j * N_ + START_] + em[r]) * LOG2E);
            }
        }
    } else {
        #pragma unroll
        for (int mt = 0; mt < 2; ++mt) {
            floatx4 st = *(const floatx4*)(trans + STOP_ * N_ + j0 + 16 * mt);
            #pragma unroll
            for (int r = 0; r < 4; ++r)
                u[mt][r] = __builtin_amdgcn_exp2f(st[r] * LOG2E);
        }
    }
    {
        float xpi[2][4] = {{1.f,1.f,1.f,1.f},{1.f,1.f,1.f,1.f}};
        if (!ISF) {   // bwd V_0 = u * exp(emit(511))
            #pragma unroll
            for (int mt = 0; mt < 2; ++mt) {
                floatx4 e = *(const floatx4*)(emitp + (size_t)511 * N_ + j0 + 16 * mt);
                #pragma unroll
                for (int r = 0; r < 4; ++r)
                    xpi[mt][r] = __builtin_amdgcn_exp2f(e[r] * LOG2E);
            }
        }
        produce();
        #pragma unroll
        for (int mt = 0; mt < 2; ++mt)
            *(int*)(sh.V[0] + wa0 + (mt << 9)) =
                pk_bf8x4(u[mt][0] * xpi[mt][0], u[mt][1] * xpi[mt][1],
                         u[mt][2] * xpi[mt][2], u[mt][3] * xpi[mt][3]);
    }
    // 2-slot emit/mask prefetch (statically indexed after inlining)
    floatx4 ebuf[2][2];
    float   mrot[2];
    ebuf[0][0] = *(const floatx4*)(emitp + (size_t)EIDX(1) * N_ + j0);
    ebuf[0][1] = *(const floatx4*)(emitp + (size_t)EIDX(1) * N_ + j0 + 16);
    ebuf[1][0] = *(const floatx4*)(emitp + (size_t)EIDX(2) * N_ + j0);
    ebuf[1][1] = *(const floatx4*)(emitp + (size_t)EIDX(2) * N_ + j0 + 16);
    mrot[0] = (float)maskp[MIDX(1)];
    mrot[1] = (float)maskp[MIDX(2)];
    lds_barrier();

    auto body = [&](int s, int pr, int cur) {
        const int sp = (s + 2 <= S) ? s + 2 : S;   // distance-2 prefetch
        floatx4 eC0 = *(const floatx4*)(emitp + (size_t)EIDX(sp) * N_ + j0);
        floatx4 eC1 = *(const floatx4*)(emitp + (size_t)EIDX(sp) * N_ + j0 + 16);
        const float mC = (float)maskp[MIDX(sp)];

        // B fragments: 4 contiguous b128 (zero conflicts)
        const char* vb = sh.V[pr];
        long long bf[8];
        #pragma unroll
        for (int p = 0; p < 4; ++p) {
            llx2 rd = *(const llx2*)(vb + (p << 10) + rbase);
            bf[2 * p]     = rd[0];
            bf[2 * p + 1] = rd[1];
        }

        // consume lag-1 stats -> exact pow2 rescale
        const float* mb = &sh.mbuf[b * 20];
        const float* sb = &sh.sbuf[b * 20];
        floatx4 m0 = *(const floatx4*)mb,       m1 = *(const floatx4*)(mb + 4);
        floatx4 m2 = *(const floatx4*)(mb + 8), m3 = *(const floatx4*)(mb + 12);
        floatx4 s0 = *(const floatx4*)sb,       s1 = *(const floatx4*)(sb + 4);
        floatx4 s2 = *(const floatx4*)(sb + 8), s3 = *(const floatx4*)(sb + 12);
        float cmax = fmaxf(
            fmaxf(fmaxf(fmaxf(m0[0], m0[1]), fmaxf(m0[2], m0[3])),
                  fmaxf(fmaxf(m1[0], m1[1]), fmaxf(m1[2], m1[3]))),
            fmaxf(fmaxf(fmaxf(m2[0], m2[1]), fmaxf(m2[2], m2[3])),
                  fmaxf(fmaxf(m3[0], m3[1]), fmaxf(m3[2], m3[3]))));
        float csum = (((s0[0] + s0[1]) + (s0[2] + s0[3])) +
                      ((s1[0] + s1[1]) + (s1[2] + s1[3]))) +
                     (((s2[0] + s2[1]) + (s2[2] + s2[3])) +
                      ((s3[0] + s3[1]) + (s3[2] + s3[3])));
        const uint32_t cb = __builtin_bit_cast(uint32_t, cmax);
        const int eb = (int)((cb >> 23) & 0xFFu);
        const float rs = __builtin_bit_cast(float, (uint32_t)(249 - eb) << 23); // 2^(122-eb)
        const float dCf = (float)(122 - eb);

        // xp for this step; fwd folds the rescale into the exponent
        float xpv[2][4];
        #pragma unroll
        for (int r = 0; r < 4; ++r) {
            if (ISF) {
                xpv[0][r] = __builtin_amdgcn_exp2f(fmaf(ebuf[cur][0][r], LOG2E, dCf));
                xpv[1][r] = __builtin_amdgcn_exp2f(fmaf(ebuf[cur][1][r], LOG2E, dCf));
            } else {
                xpv[0][r] = __builtin_amdgcn_exp2f(ebuf[cur][0][r] * LOG2E);
                xpv[1][r] = __builtin_amdgcn_exp2f(ebuf[cur][1][r] * LOG2E);
            }
        }

        floatx4 a0 = {0.f,0.f,0.f,0.f}, a1 = {0.f,0.f,0.f,0.f};
        floatx4 a2 = {0.f,0.f,0.f,0.f}, a3 = {0.f,0.f,0.f,0.f};
        #pragma unroll
        for (int kt = 0; kt < 4; ++kt) {   // two 4-deep half-chains per M-tile
            a0 = __builtin_amdgcn_mfma_f32_16x16x32_fp8_bf8(afrag[0][kt],     bf[kt],     a0, 0, 0, 0);
            a1 = __builtin_amdgcn_mfma_f32_16x16x32_fp8_bf8(afrag[0][kt + 4], bf[kt + 4], a1, 0, 0, 0);
            a2 = __builtin_amdgcn_mfma_f32_16x16x32_fp8_bf8(afrag[1][kt],     bf[kt],     a2, 0, 0, 0);
            a3 = __builtin_amdgcn_mfma_f32_16x16x32_fp8_bf8(afrag[1][kt + 4], bf[kt + 4], a3, 0, 0, 0);
        }

        const bool live = (mrot[cur] != 0.f);
        #pragma unroll
        for (int r = 0; r < 4; ++r) {
            const float v0 = a0[r] + a1[r], v1 = a2[r] + a3[r];
            if (ISF) {
                u[0][r] = live ? v0 * xpv[0][r] : csum * rs;   // rs folded in xpv
                u[1][r] = live ? v1 * xpv[1][r] : csum * rs;
            } else {
                u[0][r] = (live ? v0 : csum) * rs;
                u[1][r] = (live ? v1 : csum) * rs;
            }
        }
        C += (float)(eb - 122);

        produce();
        // write V: fwd V=u ; bwd V=u*xp  (4-way banks but only 16 cyc traffic)
        #pragma unroll
        for (int mt = 0; mt < 2; ++mt) {
            *(int*)(sh.V[pr ^ 1] + wa0 + (mt << 9)) = ISF
                ? pk_bf8x4(u[mt][0], u[mt][1], u[mt][2], u[mt][3])
                : pk_bf8x4(u[mt][0] * xpv[mt][0], u[mt][1] * xpv[mt][1],
                           u[mt][2] * xpv[mt][2], u[mt][3] * xpv[mt][3]);
        }
        lds_barrier();
        ebuf[cur][0] = eC0; ebuf[cur][1] = eC1;
        mrot[cur] = mC;
    };

    #pragma unroll 1
    for (int g = 0; g < 127; ++g) {
        body(2 * g + 1, 0, 0);
        body(2 * g + 2, 1, 1);
    }
    if (ISF) { body(255, 0, 0); body(256, 1, 1); }
    else     { body(255, 0, 0); }

    // ---- store partials: u = alpha(256) (fwd) / beta(256) (bwd), scale 2^-C
    float* wsV = ws + (ISF ? 0 : WSB_OFF);
    #pragma unroll
    for (int mt = 0; mt < 2; ++mt) {
        floatx4 vv = {u[mt][0], u[mt][1], u[mt][2], u[mt][3]};
        *(floatx4*)&wsV[(size_t)bg * N_ + j0 + 16 * mt] = vv;
    }
    if (tid < 16) {
        float* wsC = ws + (ISF ? WCF_OFF : WCB_OFF);
        wsC[blkLocal * GCOLS + tid] = C;
    }
}

__global__ __launch_bounds__(512, 2) void crf_main(
    const float* __restrict__ inputs, const float* __restrict__ trans,
    const int* __restrict__ tags, const int* __restrict__ mask,
    float* __restrict__ out, float* __restrict__ ws)
{
    __shared__ DenomShared sh;

    if (blockIdx.x >= ND) {
        // ---------------- numerator: one batch per block ----------------
        float* nred = sh.mbuf;
        int*   nredi = (int*)sh.sbuf;
        const int bb = blockIdx.x - ND;
        const int t  = threadIdx.x;            // 0..511
        const int tg = tags[bb * T_ + t];
        const float fm = (float)mask[bb * T_ + t];
        float part = 0.f;
        if (t >= 1)      part += trans[tg * N_ + tags[bb * T_ + t - 1]] * fm;
        if (t <= T_ - 2) part += inputs[((size_t)bb * T_ + t) * N_ + tg] * fm;
        int ms = mask[bb * T_ + t];
        #pragma unroll
        for (int off = 1; off < 64; off <<= 1) {
            part += __shfl_xor(part, off, 64);
            ms   += __shfl_xor(ms, off, 64);
        }
        if ((t & 63) == 0) { nred[t >> 6] = part; nredi[t >> 6] = ms; }
        __syncthreads();
        if (t == 0) {
            float tot = 0.f; int mtot = 0;
            for (int i = 0; i < 8; ++i) { tot += nred[i]; mtot += nredi[i]; }
            tot += trans[tags[bb * T_] * N_ + START_];
            const int last = mtot - 1;
            const int lt = tags[bb * T_ + last];
            tot += trans[STOP_ * N_ + lt]
                 + inputs[((size_t)bb * T_ + (T_ - 1)) * N_ + lt]
                   * (float)mask[bb * T_ + T_ - 1];
            atomicAdd(out, tot);
        }
        return;
    }

    if (blockIdx.x < NF) denom_path<true>(sh, inputs, trans, mask, ws, blockIdx.x);
    else                 denom_path<false>(sh, inputs, trans, mask, ws, blockIdx.x - NF);
}

// denom_b = LN2 * (CF_b + CB_b + log2(sum_j alphaF[b][j] * betaB[b][j]))
__global__ __launch_bounds__(256) void crf_combine(
    const float* __restrict__ ws, float* __restrict__ out)
{
    __shared__ float red[4];
    const int bb = blockIdx.x;
    const int t = threadIdx.x;
    float p = ws[(size_t)bb * N_ + t] * ws[WSB_OFF + (size_t)bb * N_ + t];
    #pragma unroll
    for (int off = 1; off < 64; off <<= 1) p += __shfl_xor(p, off, 64);
    if ((t & 63) == 0) red[t >> 6] = p;
    __syncthreads();
    if (t == 0) {
        const float tot = red[0] + red[1] + red[2] + red[3];
        const float denom = (ws[WCF_OFF + bb] + ws[WCB_OFF + bb]
                             + __builtin_amdgcn_logf(tot)) * LN2;
        atomicAdd(out, -denom);
    }
}

extern "C" void kernel_launch(void* const* d_in, const int* in_sizes, int n_in,
                              void* d_out, int out_size, void* d_ws, size_t ws_size,
                              hipStream_t stream) {
    const float* inputs = (const float*)d_in[0];
    const float* trans  = (const float*)d_in[1];
    const int*   tags   = (const int*)d_in[2];
    const int*   mask   = (const int*)d_in[3];
    float* out = (float*)d_out;
    float* ws  = (float*)d_ws;
    hipMemsetAsync(out, 0, sizeof(float), stream);
    crf_main<<<dim3(ND + B_), dim3(512), 0, stream>>>(inputs, trans, tags, mask, out, ws);
    crf_combine<<<dim3(B_), dim3(256), 0, stream>>>(ws, out);
}